// Round 1
// baseline (735.427 us; speedup 1.0000x reference)
//
#include <hip/hip_runtime.h>
#include <hip/hip_bf16.h>
#include <math.h>

#define PROJ_EPSF 0.004f
#define MIN_NORMF 1e-15f
#define ATANH_EPSF 1e-5f
#define WEI_EPSF 1e-3f

#define TT 1024
#define CC 768
#define HH 12
#define DD 64
#define BBATCH 4

// ---------------- GEMM: C[M,N] = A[M,K] * B[N,K]^T (fp32) ----------------
// 64x64 tile, BK=16, 256 threads, 4x4 accumulator per thread.
__global__ __launch_bounds__(256) void gemm_abt(const float* __restrict__ A,
                                                const float* __restrict__ B,
                                                float* __restrict__ C,
                                                int M, int N, int K) {
    __shared__ float As[16][64];
    __shared__ float Bs[16][64];
    const int tid = threadIdx.x;
    const int m0 = blockIdx.y << 6;
    const int n0 = blockIdx.x << 6;
    const int tm = tid >> 4, tn = tid & 15;
    const int lm = tid >> 2, lk = (tid & 3) << 2;
    float acc[4][4] = {};
    const float* Aptr = A + (size_t)(m0 + lm) * K + lk;
    const float* Bptr = B + (size_t)(n0 + lm) * K + lk;
    for (int k0 = 0; k0 < K; k0 += 16) {
        float4 a4 = *(const float4*)(Aptr + k0);
        float4 b4 = *(const float4*)(Bptr + k0);
        __syncthreads();
        As[lk + 0][lm] = a4.x; As[lk + 1][lm] = a4.y;
        As[lk + 2][lm] = a4.z; As[lk + 3][lm] = a4.w;
        Bs[lk + 0][lm] = b4.x; Bs[lk + 1][lm] = b4.y;
        Bs[lk + 2][lm] = b4.z; Bs[lk + 3][lm] = b4.w;
        __syncthreads();
#pragma unroll
        for (int k = 0; k < 16; ++k) {
            float a[4], b[4];
            *(float4*)a = *(const float4*)&As[k][tm << 2];
            *(float4*)b = *(const float4*)&Bs[k][tn << 2];
#pragma unroll
            for (int ii = 0; ii < 4; ++ii)
#pragma unroll
                for (int jj = 0; jj < 4; ++jj)
                    acc[ii][jj] = fmaf(a[ii], b[jj], acc[ii][jj]);
        }
    }
#pragma unroll
    for (int ii = 0; ii < 4; ++ii) {
        float4 o = make_float4(acc[ii][0], acc[ii][1], acc[ii][2], acc[ii][3]);
        *(float4*)&C[(size_t)(m0 + (tm << 2) + ii) * N + n0 + (tn << 2)] = o;
    }
}

// ---------------- Fused hyperbolic attention ----------------
// One block = one (b, h, 64-query tile). Loops over key tiles jt <= it.
// num/den accumulated in registers (all weights > 0, no rescale needed).
__global__ __launch_bounds__(256) void hyp_attn(const float* __restrict__ qkv,
                                                const float* __restrict__ kcurv,
                                                float* __restrict__ y) {
    const int it = blockIdx.x;
    const int h = blockIdx.y;
    const int b = blockIdx.z;
    const int tid = threadIdx.x;

    __shared__ float qs[64][65];   // projected q tile (scalar reads, stride 65)
    __shared__ float ks[64][65];   // projected k tile
    __shared__ float vs[64][64];   // v tile (float4 reads, stride 64)
    __shared__ float ws[64][65];   // wei tile
    __shared__ float x2s[64];
    __shared__ float y2s[64];

    const float kc = kcurv[h];
    const float sk = sqrtf(kc);
    const float maxnorm = (1.0f - PROJ_EPSF) / sk;
    const float two_over_sk = 2.0f / sk;

    const int i0 = it << 6;

    // ---- load Q tile (coalesced float4, scatter to stride-65 LDS) ----
    {
        const int li = tid >> 4;
        const int ld = (tid & 15) << 2;
#pragma unroll
        for (int p = 0; p < 4; ++p) {
            const int row = li + (p << 4);
            float4 v4 = *(const float4*)&qkv[(size_t)(b * TT + i0 + row) * (3 * CC) + h * DD + ld];
            qs[row][ld + 0] = v4.x; qs[row][ld + 1] = v4.y;
            qs[row][ld + 2] = v4.z; qs[row][ld + 3] = v4.w;
        }
    }
    __syncthreads();
    // ---- project q rows to Poincare ball: 64 rows x 4 threads each ----
    {
        const int r = tid >> 2, g = tid & 3;
        float s = 0.f;
#pragma unroll
        for (int d = 0; d < 16; ++d) { float v = qs[r][(g << 4) + d]; s = fmaf(v, v, s); }
        s += __shfl_xor(s, 1);
        s += __shfl_xor(s, 2);
        const float sum = s;
        const float norm = sqrtf(fmaxf(sum, MIN_NORMF));
        float x2 = sum;
        if (norm > maxnorm) {
            const float scale = maxnorm / norm;
#pragma unroll
            for (int d = 0; d < 16; ++d) qs[r][(g << 4) + d] *= scale;
            x2 = sum * scale * scale;
        }
        if (g == 0) x2s[r] = x2;
    }

    float num[16] = {};
    float den = 0.f;
    const int pi = tid >> 2;          // phase-2 row
    const int pd = (tid & 3) << 4;    // phase-2 d base
    const int tm = tid >> 4, tn = tid & 15;

    for (int jt = 0; jt <= it; ++jt) {
        const int j0 = jt << 6;
        __syncthreads();  // protect ks/vs/ws from previous iteration's readers
        // ---- load K,V tiles ----
        {
            const int li = tid >> 4;
            const int ld = (tid & 15) << 2;
#pragma unroll
            for (int p = 0; p < 4; ++p) {
                const int row = li + (p << 4);
                const size_t base = (size_t)(b * TT + j0 + row) * (3 * CC) + h * DD + ld;
                float4 k4 = *(const float4*)&qkv[base + CC];
                float4 v4 = *(const float4*)&qkv[base + 2 * CC];
                ks[row][ld + 0] = k4.x; ks[row][ld + 1] = k4.y;
                ks[row][ld + 2] = k4.z; ks[row][ld + 3] = k4.w;
                *(float4*)&vs[row][ld] = v4;
            }
        }
        __syncthreads();
        // ---- project k rows ----
        {
            const int r = tid >> 2, g = tid & 3;
            float s = 0.f;
#pragma unroll
            for (int d = 0; d < 16; ++d) { float v = ks[r][(g << 4) + d]; s = fmaf(v, v, s); }
            s += __shfl_xor(s, 1);
            s += __shfl_xor(s, 2);
            const float sum = s;
            const float norm = sqrtf(fmaxf(sum, MIN_NORMF));
            float y2 = sum;
            if (norm > maxnorm) {
                const float scale = maxnorm / norm;
#pragma unroll
                for (int d = 0; d < 16; ++d) ks[r][(g << 4) + d] *= scale;
                y2 = sum * scale * scale;
            }
            if (g == 0) y2s[r] = y2;
        }
        __syncthreads();
        // ---- S = qp . kp^T : 16x16 threads, 4x4 each ----
        float acc[4][4] = {};
        for (int d = 0; d < 64; ++d) {
            float a[4], bb[4];
#pragma unroll
            for (int u = 0; u < 4; ++u) a[u] = qs[(tm << 2) + u][d];
#pragma unroll
            for (int u = 0; u < 4; ++u) bb[u] = ks[(tn << 2) + u][d];
#pragma unroll
            for (int ii = 0; ii < 4; ++ii)
#pragma unroll
                for (int jj = 0; jj < 4; ++jj)
                    acc[ii][jj] = fmaf(a[ii], bb[jj], acc[ii][jj]);
        }
        // ---- hyperbolic transform -> wei -> ws ----
#pragma unroll
        for (int ii = 0; ii < 4; ++ii) {
            const int ig = i0 + (tm << 2) + ii;
            const float x2 = x2s[(tm << 2) + ii];
#pragma unroll
            for (int jj = 0; jj < 4; ++jj) {
                const int jg = j0 + (tn << 2) + jj;
                const float y2 = y2s[(tn << 2) + jj];
                const float xy = acc[ii][jj];
                const float Aa = 1.0f - 2.0f * kc * xy + kc * y2;
                const float Bc = 1.0f - kc * x2;
                const float num2 = Aa * Aa * x2 + Bc * Bc * y2 - 2.0f * Aa * Bc * xy;
                const float den2 = 1.0f - 2.0f * kc * xy + kc * kc * x2 * y2;
                const float madd = sqrtf(fmaxf(num2, MIN_NORMF)) / fmaxf(den2, MIN_NORMF);
                float tcl = sk * madd;
                tcl = fminf(fmaxf(tcl, 0.0f), 1.0f - ATANH_EPSF);
                const float dist = two_over_sk * atanhf(tcl);
                float w = 1.0f / (WEI_EPSF + dist * dist);
                if (jg > ig) w = 0.0f;   // causal mask
                ws[(tm << 2) + ii][(tn << 2) + jj] = w;
            }
        }
        __syncthreads();
        // ---- accumulate num += wei * v, den += wei ----
        for (int j = 0; j < 64; ++j) {
            const float w = ws[pi][j];
            den += w;
#pragma unroll
            for (int q = 0; q < 4; ++q) {
                float4 v4 = *(const float4*)&vs[j][pd + (q << 2)];
                num[(q << 2) + 0] = fmaf(w, v4.x, num[(q << 2) + 0]);
                num[(q << 2) + 1] = fmaf(w, v4.y, num[(q << 2) + 1]);
                num[(q << 2) + 2] = fmaf(w, v4.z, num[(q << 2) + 2]);
                num[(q << 2) + 3] = fmaf(w, v4.w, num[(q << 2) + 3]);
            }
        }
    }
    // ---- epilogue: y = num/den, write (B,T,C) layout ----
    const float inv = 1.0f / den;
    float* yp = &y[(size_t)(b * TT + i0 + pi) * CC + h * DD + pd];
#pragma unroll
    for (int q = 0; q < 4; ++q) {
        float4 o = make_float4(num[(q << 2) + 0] * inv, num[(q << 2) + 1] * inv,
                               num[(q << 2) + 2] * inv, num[(q << 2) + 3] * inv);
        *(float4*)&yp[q << 2] = o;
    }
}

extern "C" void kernel_launch(void* const* d_in, const int* in_sizes, int n_in,
                              void* d_out, int out_size, void* d_ws, size_t ws_size,
                              hipStream_t stream) {
    const float* x     = (const float*)d_in[0];   // (4,1024,768)
    const float* Wqkv  = (const float*)d_in[1];   // (2304,768)
    const float* Wproj = (const float*)d_in[2];   // (768,768)
    const float* kcurv = (const float*)d_in[3];   // (1,12,1,1)
    float* out = (float*)d_out;

    const int M = BBATCH * TT;                    // 4096
    float* qkv = (float*)d_ws;                    // M x 3C
    float* y   = qkv + (size_t)M * 3 * CC;        // M x C

    // 1) qkv = x @ Wqkv^T
    gemm_abt<<<dim3(3 * CC / 64, M / 64), 256, 0, stream>>>(x, Wqkv, qkv, M, 3 * CC, CC);
    // 2) fused hyperbolic attention -> y (B,T,C)
    hyp_attn<<<dim3(TT / 64, HH, BBATCH), 256, 0, stream>>>(qkv, kcurv, y);
    // 3) out = y @ Wproj^T
    gemm_abt<<<dim3(CC / 64, M / 64), 256, 0, stream>>>(y, Wproj, out, M, CC, CC);
}

// Round 2
// 583.429 us; speedup vs baseline: 1.2605x; 1.2605x over previous
//
#include <hip/hip_runtime.h>
#include <hip/hip_bf16.h>
#include <math.h>

#define PROJ_EPSF 0.004f
#define MIN_NORMF 1e-15f
#define ATANH_EPSF 1e-5f
#define WEI_EPSF 1e-3f
#define LN2F 0.69314718055994531f

#define TT 1024
#define CC 768
#define HH 12
#define DD 64
#define BBATCH 4

// ---------------- GEMM: C[M,N] = A[M,K] * B[N,K]^T (fp32) ----------------
__global__ __launch_bounds__(256) void gemm_abt(const float* __restrict__ A,
                                                const float* __restrict__ B,
                                                float* __restrict__ C,
                                                int M, int N, int K) {
    __shared__ float As[16][64];
    __shared__ float Bs[16][64];
    const int tid = threadIdx.x;
    const int m0 = blockIdx.y << 6;
    const int n0 = blockIdx.x << 6;
    const int tm = tid >> 4, tn = tid & 15;
    const int lm = tid >> 2, lk = (tid & 3) << 2;
    float acc[4][4] = {};
    const float* Aptr = A + (size_t)(m0 + lm) * K + lk;
    const float* Bptr = B + (size_t)(n0 + lm) * K + lk;
    for (int k0 = 0; k0 < K; k0 += 16) {
        float4 a4 = *(const float4*)(Aptr + k0);
        float4 b4 = *(const float4*)(Bptr + k0);
        __syncthreads();
        As[lk + 0][lm] = a4.x; As[lk + 1][lm] = a4.y;
        As[lk + 2][lm] = a4.z; As[lk + 3][lm] = a4.w;
        Bs[lk + 0][lm] = b4.x; Bs[lk + 1][lm] = b4.y;
        Bs[lk + 2][lm] = b4.z; Bs[lk + 3][lm] = b4.w;
        __syncthreads();
#pragma unroll
        for (int k = 0; k < 16; ++k) {
            float a[4], b[4];
            *(float4*)a = *(const float4*)&As[k][tm << 2];
            *(float4*)b = *(const float4*)&Bs[k][tn << 2];
#pragma unroll
            for (int ii = 0; ii < 4; ++ii)
#pragma unroll
                for (int jj = 0; jj < 4; ++jj)
                    acc[ii][jj] = fmaf(a[ii], b[jj], acc[ii][jj]);
        }
    }
#pragma unroll
    for (int ii = 0; ii < 4; ++ii) {
        float4 o = make_float4(acc[ii][0], acc[ii][1], acc[ii][2], acc[ii][3]);
        *(float4*)&C[(size_t)(m0 + (tm << 2) + ii) * N + n0 + (tn << 2)] = o;
    }
}

// ---------------- Fused hyperbolic attention (512 threads) ----------------
// qs swizzled by (r&7); ks swizzled by ((r>>2)&7); vs linear; ws stride 65.
__global__ __launch_bounds__(512) void hyp_attn(const float* __restrict__ qkv,
                                                const float* __restrict__ kcurv,
                                                float* __restrict__ y) {
    const int it = (TT / 64 - 1) - blockIdx.x;   // long blocks first
    const int h = blockIdx.y;
    const int b = blockIdx.z;
    const int tid = threadIdx.x;

    __shared__ float qs[64][64];
    __shared__ float ks[64][64];
    __shared__ float vs[64][64];
    __shared__ float ws[64][65];
    __shared__ float x2s[64];
    __shared__ float y2s[64];

    const float kc = kcurv[h];
    const float sk = sqrtf(kc);
    const float maxnorm = (1.0f - PROJ_EPSF) / sk;
    const float distc = LN2F / sk;   // dist = distc * log2(ratio)

    const int i0 = it << 6;
    const int li = tid >> 4;          // 0..31 load row
    const int lc = tid & 15;          // float4 group
    const int tm = tid >> 4;          // S rows 2tm,2tm+1
    const int tn = tid & 15;          // S cols 4tn..+3
    const int r2 = tid >> 3;          // phase-2 row
    const int g2 = tid & 7;           // phase-2 d-group (8 floats)

    // ---- load Q tile ----
#pragma unroll
    for (int p = 0; p < 2; ++p) {
        const int r = li + (p << 5);
        float4 v4 = *(const float4*)&qkv[(size_t)(b * TT + i0 + r) * (3 * CC) + h * DD + (lc << 2)];
        *(float4*)&qs[r][(lc ^ (r & 7)) << 2] = v4;
    }
    __syncthreads();
    // ---- project q rows (8 lanes per row) ----
    {
        const int r = r2, g = g2;
        float4 a = *(const float4*)&qs[r][((2 * g) ^ (r & 7)) << 2];
        float4 c = *(const float4*)&qs[r][((2 * g + 1) ^ (r & 7)) << 2];
        float s = a.x * a.x + a.y * a.y + a.z * a.z + a.w * a.w
                + c.x * c.x + c.y * c.y + c.z * c.z + c.w * c.w;
        s += __shfl_xor(s, 1); s += __shfl_xor(s, 2); s += __shfl_xor(s, 4);
        float x2 = s;
        const float norm = sqrtf(fmaxf(s, MIN_NORMF));
        if (norm > maxnorm) {
            const float scale = maxnorm / norm;
            a.x *= scale; a.y *= scale; a.z *= scale; a.w *= scale;
            c.x *= scale; c.y *= scale; c.z *= scale; c.w *= scale;
            *(float4*)&qs[r][((2 * g) ^ (r & 7)) << 2] = a;
            *(float4*)&qs[r][((2 * g + 1) ^ (r & 7)) << 2] = c;
            x2 = s * scale * scale;
        }
        if (g == 0) x2s[r] = x2;
    }

    float num[8] = {};
    float den = 0.f;

    for (int jt = 0; jt <= it; ++jt) {
        const int j0 = jt << 6;
        __syncthreads();   // prev readers of ks/vs/ws done; q projection done
        // ---- load K,V tiles ----
#pragma unroll
        for (int p = 0; p < 2; ++p) {
            const int r = li + (p << 5);
            const size_t base = (size_t)(b * TT + j0 + r) * (3 * CC) + h * DD + (lc << 2);
            float4 k4 = *(const float4*)&qkv[base + CC];
            float4 v4 = *(const float4*)&qkv[base + 2 * CC];
            *(float4*)&ks[r][(lc ^ ((r >> 2) & 7)) << 2] = k4;
            *(float4*)&vs[r][lc << 2] = v4;
        }
        __syncthreads();
        // ---- project k rows ----
        {
            const int r = r2, g = g2;
            const int sw = (r >> 2) & 7;
            float4 a = *(const float4*)&ks[r][((2 * g) ^ sw) << 2];
            float4 c = *(const float4*)&ks[r][((2 * g + 1) ^ sw) << 2];
            float s = a.x * a.x + a.y * a.y + a.z * a.z + a.w * a.w
                    + c.x * c.x + c.y * c.y + c.z * c.z + c.w * c.w;
            s += __shfl_xor(s, 1); s += __shfl_xor(s, 2); s += __shfl_xor(s, 4);
            float y2v = s;
            const float norm = sqrtf(fmaxf(s, MIN_NORMF));
            if (norm > maxnorm) {
                const float scale = maxnorm / norm;
                a.x *= scale; a.y *= scale; a.z *= scale; a.w *= scale;
                c.x *= scale; c.y *= scale; c.z *= scale; c.w *= scale;
                *(float4*)&ks[r][((2 * g) ^ sw) << 2] = a;
                *(float4*)&ks[r][((2 * g + 1) ^ sw) << 2] = c;
                y2v = s * scale * scale;
            }
            if (g == 0) y2s[r] = y2v;
        }
        __syncthreads();
        // ---- S = qp . kp^T (2x4 per thread, float4 over d) ----
        float acc[2][4] = {};
#pragma unroll 4
        for (int dq = 0; dq < 16; ++dq) {
            const int ra = 2 * tm, rb = 2 * tm + 1;
            float4 qa = *(const float4*)&qs[ra][(dq ^ (ra & 7)) << 2];
            float4 qb = *(const float4*)&qs[rb][(dq ^ (rb & 7)) << 2];
            float4 kb[4];
#pragma unroll
            for (int v = 0; v < 4; ++v)
                kb[v] = *(const float4*)&ks[4 * tn + v][(dq ^ (tn & 7)) << 2];
#pragma unroll
            for (int v = 0; v < 4; ++v) {
                acc[0][v] += qa.x * kb[v].x + qa.y * kb[v].y + qa.z * kb[v].z + qa.w * kb[v].w;
                acc[1][v] += qb.x * kb[v].x + qb.y * kb[v].y + qb.z * kb[v].z + qb.w * kb[v].w;
            }
        }
        // ---- hyperbolic transform -> ws ----
#pragma unroll
        for (int u = 0; u < 2; ++u) {
            const int i = 2 * tm + u;
            const float x2 = x2s[i];
            const float Bc = 1.0f - kc * x2;
            const int ig = i0 + i;
#pragma unroll
            for (int v = 0; v < 4; ++v) {
                const int j = 4 * tn + v;
                const float y2 = y2s[j];
                const float xy = acc[u][v];
                const float Aa = 1.0f - 2.0f * kc * xy + kc * y2;
                const float num2 = Aa * Aa * x2 + Bc * Bc * y2 - 2.0f * Aa * Bc * xy;
                const float den2 = 1.0f - 2.0f * kc * xy + kc * kc * x2 * y2;
                const float madd = sqrtf(fmaxf(num2, MIN_NORMF)) *
                                   __builtin_amdgcn_rcpf(fmaxf(den2, MIN_NORMF));
                float t = sk * madd;
                t = fminf(fmaxf(t, 0.0f), 1.0f - ATANH_EPSF);
                const float dist = distc * __builtin_amdgcn_logf((1.0f + t) *
                                           __builtin_amdgcn_rcpf(1.0f - t));
                float w = __builtin_amdgcn_rcpf(WEI_EPSF + dist * dist);
                if (j0 + j > ig) w = 0.0f;   // causal
                ws[i][j] = w;
            }
        }
        __syncthreads();
        // ---- num += wei*v, den += wei ----
#pragma unroll 4
        for (int j = 0; j < 64; ++j) {
            const float w = ws[r2][j];
            den += w;
            float4 v0 = *(const float4*)&vs[j][g2 << 3];
            float4 v1 = *(const float4*)&vs[j][(g2 << 3) + 4];
            num[0] = fmaf(w, v0.x, num[0]); num[1] = fmaf(w, v0.y, num[1]);
            num[2] = fmaf(w, v0.z, num[2]); num[3] = fmaf(w, v0.w, num[3]);
            num[4] = fmaf(w, v1.x, num[4]); num[5] = fmaf(w, v1.y, num[5]);
            num[6] = fmaf(w, v1.z, num[6]); num[7] = fmaf(w, v1.w, num[7]);
        }
    }
    // ---- epilogue ----
    const float inv = __builtin_amdgcn_rcpf(den);
    float* yp = &y[(size_t)(b * TT + i0 + r2) * CC + h * DD + (g2 << 3)];
    float4 o0 = make_float4(num[0] * inv, num[1] * inv, num[2] * inv, num[3] * inv);
    float4 o1 = make_float4(num[4] * inv, num[5] * inv, num[6] * inv, num[7] * inv);
    *(float4*)&yp[0] = o0;
    *(float4*)&yp[4] = o1;
}

extern "C" void kernel_launch(void* const* d_in, const int* in_sizes, int n_in,
                              void* d_out, int out_size, void* d_ws, size_t ws_size,
                              hipStream_t stream) {
    const float* x     = (const float*)d_in[0];   // (4,1024,768)
    const float* Wqkv  = (const float*)d_in[1];   // (2304,768)
    const float* Wproj = (const float*)d_in[2];   // (768,768)
    const float* kcurv = (const float*)d_in[3];   // (1,12,1,1)
    float* out = (float*)d_out;

    const int M = BBATCH * TT;                    // 4096
    float* qkv = (float*)d_ws;                    // M x 3C
    float* y   = qkv + (size_t)M * 3 * CC;        // M x C

    gemm_abt<<<dim3(3 * CC / 64, M / 64), 256, 0, stream>>>(x, Wqkv, qkv, M, 3 * CC, CC);
    hyp_attn<<<dim3(TT / 64, HH, BBATCH), 512, 0, stream>>>(qkv, kcurv, y);
    gemm_abt<<<dim3(CC / 64, M / 64), 256, 0, stream>>>(y, Wproj, out, M, CC, CC);
}

// Round 3
// 282.384 us; speedup vs baseline: 2.6044x; 2.0661x over previous
//
#include <hip/hip_runtime.h>
#include <hip/hip_bf16.h>
#include <math.h>

#define PROJ_EPSF 0.004f
#define MIN_NORMF 1e-15f
#define ATANH_EPSF 1e-5f
#define WEI_EPSF 1e-3f
#define LN2F 0.69314718055994531f

#define TT 1024
#define CC 768
#define HH 12
#define DD 64
#define BBATCH 4

typedef __attribute__((ext_vector_type(4))) float f32x4;
typedef __attribute__((ext_vector_type(8))) short bf16x8;

#define MFMA(a, b, c) __builtin_amdgcn_mfma_f32_16x16x32_bf16(a, b, c, 0, 0, 0)

static __device__ __forceinline__ ushort f2bf(float f) {
    uint u = __float_as_uint(f);
    u += 0x7fffu + ((u >> 16) & 1u);
    return (ushort)(u >> 16);
}
static __device__ __forceinline__ float bf2f(ushort h) {
    return __uint_as_float(((uint)h) << 16);
}
static __device__ __forceinline__ void cvt4(float4 v, unsigned long long& hp, unsigned long long& lp) {
    ushort h0 = f2bf(v.x), h1 = f2bf(v.y), h2 = f2bf(v.z), h3 = f2bf(v.w);
    ushort l0 = f2bf(v.x - bf2f(h0)), l1 = f2bf(v.y - bf2f(h1));
    ushort l2 = f2bf(v.z - bf2f(h2)), l3 = f2bf(v.w - bf2f(h3));
    hp = (unsigned long long)h0 | ((unsigned long long)h1 << 16) |
         ((unsigned long long)h2 << 32) | ((unsigned long long)h3 << 48);
    lp = (unsigned long long)l0 | ((unsigned long long)l1 << 16) |
         ((unsigned long long)l2 << 32) | ((unsigned long long)l3 << 48);
}

// ---------------- GEMM: C[M,N] = A[M,K]*B[N,K]^T via bf16 hi/lo MFMA ----------------
// 128x128 tile, BK=32, 256 threads = 4 waves (2x2), wave = 64x64 = 4x4 16x16 frags.
__global__ __launch_bounds__(256) void gemm_abt_mfma(const float* __restrict__ A,
                                                     const float* __restrict__ B,
                                                     float* __restrict__ C,
                                                     int M, int N, int K) {
    __shared__ ushort Ah[128 * 40], Al[128 * 40], Bh[128 * 40], Bl[128 * 40];
    const int tid = threadIdx.x;
    const int lane = tid & 63;
    const int wv = tid >> 6;
    const int wr = wv >> 1, wc = wv & 1;
    const int lr = lane & 15, lg = lane >> 4;
    const int m0 = blockIdx.y * 128, n0 = blockIdx.x * 128;
    const int srow = tid >> 1, sk0 = (tid & 1) * 16;

    f32x4 acc[4][4] = {};

    const float* Ap = A + (size_t)(m0 + srow) * K + sk0;
    const float* Bp = B + (size_t)(n0 + srow) * K + sk0;

    for (int kk = 0; kk < K; kk += 32) {
        float4 av[4], bv[4];
#pragma unroll
        for (int q = 0; q < 4; ++q) {
            av[q] = *(const float4*)(Ap + kk + 4 * q);
            bv[q] = *(const float4*)(Bp + kk + 4 * q);
        }
        __syncthreads();
#pragma unroll
        for (int q = 0; q < 4; ++q) {
            unsigned long long hp, lp;
            cvt4(av[q], hp, lp);
            *(unsigned long long*)&Ah[srow * 40 + sk0 + 4 * q] = hp;
            *(unsigned long long*)&Al[srow * 40 + sk0 + 4 * q] = lp;
            cvt4(bv[q], hp, lp);
            *(unsigned long long*)&Bh[srow * 40 + sk0 + 4 * q] = hp;
            *(unsigned long long*)&Bl[srow * 40 + sk0 + 4 * q] = lp;
        }
        __syncthreads();
        bf16x8 ah[4], al_[4];
#pragma unroll
        for (int m = 0; m < 4; ++m) {
            const int off = (wr * 64 + m * 16 + lr) * 40 + lg * 8;
            ah[m] = *(const bf16x8*)&Ah[off];
            al_[m] = *(const bf16x8*)&Al[off];
        }
#pragma unroll
        for (int n = 0; n < 4; ++n) {
            const int off = (wc * 64 + n * 16 + lr) * 40 + lg * 8;
            bf16x8 bh = *(const bf16x8*)&Bh[off];
            bf16x8 bl = *(const bf16x8*)&Bl[off];
#pragma unroll
            for (int m = 0; m < 4; ++m) {
                acc[m][n] = MFMA(ah[m], bh, acc[m][n]);
                acc[m][n] = MFMA(ah[m], bl, acc[m][n]);
                acc[m][n] = MFMA(al_[m], bh, acc[m][n]);
            }
        }
    }
#pragma unroll
    for (int m = 0; m < 4; ++m)
#pragma unroll
        for (int n = 0; n < 4; ++n)
#pragma unroll
            for (int r = 0; r < 4; ++r)
                C[(size_t)(m0 + wr * 64 + m * 16 + lg * 4 + r) * N + n0 + wc * 64 + n * 16 + lr] =
                    acc[m][n][r];
}

// ---------------- Fused hyperbolic attention, MFMA ----------------
// Block = (b,h,64-q-tile), 256 threads = 4 waves; wave owns 16 q-rows.
// S = (qh+ql)(kh+kl)^T via 3-term hi/lo MFMA (f32-grade -> safe through the
// cancellation-heavy transform); wei/V in plain bf16 for PV.
__global__ __launch_bounds__(256) void hyp_attn_mfma(const float* __restrict__ qkv,
                                                     const float* __restrict__ kcurv,
                                                     float* __restrict__ y) {
    const int it = (TT / 64 - 1) - (int)blockIdx.x;   // long blocks first
    const int h = blockIdx.y, b = blockIdx.z;
    const int tid = threadIdx.x;
    const int lane = tid & 63, wv = tid >> 6;
    const int lr = lane & 15, lg = lane >> 4;
    const int row = tid >> 2, g = tid & 3;            // staging map: 4 thr/row

    __shared__ ushort qh[64 * 72], ql[64 * 72], kh[64 * 72], kl[64 * 72];
    __shared__ ushort wt[64 * 72], vt[64 * 72];
    __shared__ float x2s[64], y2s[64];

    const float kc = kcurv[h];
    const float sk = sqrtf(kc);
    const float maxnorm = (1.0f - PROJ_EPSF) / sk;
    const float distc = LN2F / sk;   // dist = distc * log2((1+t)/(1-t))

    const int i0 = it << 6;

    // ---- stage Q with Poincare projection (f32 regs -> hi/lo bf16 LDS) ----
    {
        const float* src = qkv + (size_t)(b * TT + i0 + row) * (3 * CC) + h * DD + g * 16;
        float4 f[4];
#pragma unroll
        for (int q = 0; q < 4; ++q) f[q] = *(const float4*)(src + 4 * q);
        float s = 0.f;
#pragma unroll
        for (int q = 0; q < 4; ++q)
            s += f[q].x * f[q].x + f[q].y * f[q].y + f[q].z * f[q].z + f[q].w * f[q].w;
        s += __shfl_xor(s, 1);
        s += __shfl_xor(s, 2);
        float x2 = s;
        const float norm = sqrtf(fmaxf(s, MIN_NORMF));
        if (norm > maxnorm) {
            const float sc = maxnorm / norm;
#pragma unroll
            for (int q = 0; q < 4; ++q) {
                f[q].x *= sc; f[q].y *= sc; f[q].z *= sc; f[q].w *= sc;
            }
            x2 = s * sc * sc;
        }
#pragma unroll
        for (int q = 0; q < 4; ++q) {
            unsigned long long hp, lp;
            cvt4(f[q], hp, lp);
            *(unsigned long long*)&qh[row * 72 + g * 16 + q * 4] = hp;
            *(unsigned long long*)&ql[row * 72 + g * 16 + q * 4] = lp;
        }
        if (g == 0) x2s[row] = x2;
    }

    f32x4 pv[4] = {};
    float den[4] = {0.f, 0.f, 0.f, 0.f};

    for (int jt = 0; jt <= it; ++jt) {
        const int j0 = jt << 6;
        __syncthreads();   // prev PV readers done; q staging done (jt==0)
        // ---- stage K with projection ----
        {
            const float* src = qkv + (size_t)(b * TT + j0 + row) * (3 * CC) + CC + h * DD + g * 16;
            float4 f[4];
#pragma unroll
            for (int q = 0; q < 4; ++q) f[q] = *(const float4*)(src + 4 * q);
            float s = 0.f;
#pragma unroll
            for (int q = 0; q < 4; ++q)
                s += f[q].x * f[q].x + f[q].y * f[q].y + f[q].z * f[q].z + f[q].w * f[q].w;
            s += __shfl_xor(s, 1);
            s += __shfl_xor(s, 2);
            float y2 = s;
            const float norm = sqrtf(fmaxf(s, MIN_NORMF));
            if (norm > maxnorm) {
                const float sc = maxnorm / norm;
#pragma unroll
                for (int q = 0; q < 4; ++q) {
                    f[q].x *= sc; f[q].y *= sc; f[q].z *= sc; f[q].w *= sc;
                }
                y2 = s * sc * sc;
            }
#pragma unroll
            for (int q = 0; q < 4; ++q) {
                unsigned long long hp, lp;
                cvt4(f[q], hp, lp);
                *(unsigned long long*)&kh[row * 72 + g * 16 + q * 4] = hp;
                *(unsigned long long*)&kl[row * 72 + g * 16 + q * 4] = lp;
            }
            if (g == 0) y2s[row] = y2;
        }
        // ---- stage V transposed, bf16 hi only: vt[d][j] ----
        {
            const float* src = qkv + (size_t)(b * TT + j0 + row) * (3 * CC) + 2 * CC + h * DD + g * 16;
#pragma unroll
            for (int q = 0; q < 4; ++q) {
                float4 v4 = *(const float4*)(src + 4 * q);
                const int d0 = g * 16 + q * 4;
                vt[(d0 + 0) * 72 + row] = f2bf(v4.x);
                vt[(d0 + 1) * 72 + row] = f2bf(v4.y);
                vt[(d0 + 2) * 72 + row] = f2bf(v4.z);
                vt[(d0 + 3) * 72 + row] = f2bf(v4.w);
            }
        }
        __syncthreads();
        // ---- S = qp . kp^T via 3-term hi/lo MFMA ----
        f32x4 sacc[4] = {};
        bf16x8 aH[2], aL[2];
#pragma unroll
        for (int ks = 0; ks < 2; ++ks) {
            const int off = (wv * 16 + lr) * 72 + ks * 32 + lg * 8;
            aH[ks] = *(const bf16x8*)&qh[off];
            aL[ks] = *(const bf16x8*)&ql[off];
        }
#pragma unroll
        for (int ks = 0; ks < 2; ++ks)
#pragma unroll
            for (int n = 0; n < 4; ++n) {
                const int off = (n * 16 + lr) * 72 + ks * 32 + lg * 8;
                bf16x8 bH = *(const bf16x8*)&kh[off];
                bf16x8 bL = *(const bf16x8*)&kl[off];
                sacc[n] = MFMA(aH[ks], bH, sacc[n]);
                sacc[n] = MFMA(aH[ks], bL, sacc[n]);
                sacc[n] = MFMA(aL[ks], bH, sacc[n]);
            }
        // ---- hyperbolic transform -> wt (bf16), den from rounded wei ----
#pragma unroll
        for (int r = 0; r < 4; ++r) {
            const int iloc = wv * 16 + lg * 4 + r;
            const float x2 = x2s[iloc];
            const float Bc = 1.0f - kc * x2;
            const int ig = i0 + iloc;
            float dsum = 0.f;
#pragma unroll
            for (int n = 0; n < 4; ++n) {
                const int jloc = n * 16 + lr;
                const float y2 = y2s[jloc];
                const float xy = sacc[n][r];
                const float Aa = 1.0f - 2.0f * kc * xy + kc * y2;
                const float num2 = Aa * Aa * x2 + Bc * Bc * y2 - 2.0f * Aa * Bc * xy;
                const float den2 = 1.0f - 2.0f * kc * xy + kc * kc * x2 * y2;
                const float madd = sqrtf(fmaxf(num2, MIN_NORMF)) *
                                   __builtin_amdgcn_rcpf(fmaxf(den2, MIN_NORMF));
                float t = sk * madd;
                t = fminf(fmaxf(t, 0.0f), 1.0f - ATANH_EPSF);
                const float dist = distc * __builtin_amdgcn_logf((1.0f + t) *
                                           __builtin_amdgcn_rcpf(1.0f - t));
                float wgt = __builtin_amdgcn_rcpf(WEI_EPSF + dist * dist);
                if (j0 + jloc > ig) wgt = 0.0f;   // causal
                const ushort wb = f2bf(wgt);
                wt[iloc * 72 + jloc] = wb;
                dsum += bf2f(wb);
            }
            dsum += __shfl_xor(dsum, 1);
            dsum += __shfl_xor(dsum, 2);
            dsum += __shfl_xor(dsum, 4);
            dsum += __shfl_xor(dsum, 8);
            den[r] += dsum;
        }
        __syncthreads();
        // ---- PV: y += wei @ V ----
#pragma unroll
        for (int ks = 0; ks < 2; ++ks) {
            const bf16x8 wf = *(const bf16x8*)&wt[(wv * 16 + lr) * 72 + ks * 32 + lg * 8];
#pragma unroll
            for (int n = 0; n < 4; ++n) {
                const bf16x8 vf = *(const bf16x8*)&vt[(n * 16 + lr) * 72 + ks * 32 + lg * 8];
                pv[n] = MFMA(wf, vf, pv[n]);
            }
        }
    }
    // ---- epilogue: y = pv/den ----
#pragma unroll
    for (int r = 0; r < 4; ++r) {
        const float iv = __builtin_amdgcn_rcpf(den[r]);
        const size_t grow = (size_t)(b * TT + i0 + wv * 16 + lg * 4 + r);
#pragma unroll
        for (int n = 0; n < 4; ++n)
            y[grow * CC + h * DD + n * 16 + lr] = pv[n][r] * iv;
    }
}

extern "C" void kernel_launch(void* const* d_in, const int* in_sizes, int n_in,
                              void* d_out, int out_size, void* d_ws, size_t ws_size,
                              hipStream_t stream) {
    const float* x     = (const float*)d_in[0];   // (4,1024,768)
    const float* Wqkv  = (const float*)d_in[1];   // (2304,768)
    const float* Wproj = (const float*)d_in[2];   // (768,768)
    const float* kcurv = (const float*)d_in[3];   // (1,12,1,1)
    float* out = (float*)d_out;

    const int M = BBATCH * TT;                    // 4096
    float* qkv = (float*)d_ws;                    // M x 3C
    float* y   = qkv + (size_t)M * 3 * CC;        // M x C

    gemm_abt_mfma<<<dim3(3 * CC / 128, M / 128), 256, 0, stream>>>(x, Wqkv, qkv, M, 3 * CC, CC);
    hyp_attn_mfma<<<dim3(TT / 64, HH, BBATCH), 256, 0, stream>>>(qkv, kcurv, y);
    gemm_abt_mfma<<<dim3(CC / 128, M / 128), 256, 0, stream>>>(y, Wproj, out, M, CC, CC);
}

// Round 4
// 240.360 us; speedup vs baseline: 3.0597x; 1.1748x over previous
//
#include <hip/hip_runtime.h>
#include <hip/hip_bf16.h>
#include <math.h>

#define PROJ_EPSF 0.004f
#define MIN_NORMF 1e-15f
#define ATANH_EPSF 1e-5f
#define WEI_EPSF 1e-3f
#define LN2F 0.69314718055994531f

#define TT 1024
#define CC 768
#define HH 12
#define BBATCH 4

typedef unsigned long long ull;
typedef __attribute__((ext_vector_type(4))) float f32x4;
typedef __attribute__((ext_vector_type(8))) short bf16x8;

#define MFMA(a, b, c) __builtin_amdgcn_mfma_f32_16x16x32_bf16(a, b, c, 0, 0, 0)

static __device__ __forceinline__ uint cvtpk(float a, float b) {
    uint r;
    asm("v_cvt_pk_bf16_f32 %0, %1, %2" : "=v"(r) : "v"(a), "v"(b));
    return r;
}
static __device__ __forceinline__ ushort f2bf(float f) {
    uint u = __float_as_uint(f);
    u += 0x7fffu + ((u >> 16) & 1u);
    return (ushort)(u >> 16);
}
static __device__ __forceinline__ float bf2f(ushort h) {
    return __uint_as_float(((uint)h) << 16);
}
// split float4 -> 4 bf16 hi (packed u64) + 4 bf16 residual-lo (packed u64)
static __device__ __forceinline__ void split4(const float4& f, ull& hp, ull& lp) {
    uint h01 = cvtpk(f.x, f.y), h23 = cvtpk(f.z, f.w);
    float r0 = f.x - __uint_as_float(h01 << 16);
    float r1 = f.y - __uint_as_float(h01 & 0xffff0000u);
    float r2 = f.z - __uint_as_float(h23 << 16);
    float r3 = f.w - __uint_as_float(h23 & 0xffff0000u);
    uint l01 = cvtpk(r0, r1), l23 = cvtpk(r2, r3);
    hp = ((ull)h23 << 32) | h01;
    lp = ((ull)l23 << 32) | l01;
}

// ---------------- weight prep: f32 -> bf16 hi/lo planes ----------------
__global__ __launch_bounds__(256) void wprep(const float* __restrict__ W,
                                             ushort* __restrict__ Wh,
                                             ushort* __restrict__ Wl, int n4) {
    int i = blockIdx.x * 256 + threadIdx.x;
    if (i < n4) {
        float4 f = ((const float4*)W)[i];
        ull hp, lp;
        split4(f, hp, lp);
        ((ull*)Wh)[i] = hp;
        ((ull*)Wl)[i] = lp;
    }
}

// ---------------- fused QKV GEMM + Poincare projection + layout ----------------
// C[M=4096, N=2304] = x @ Wqkv^T.  q/k tiles: project rows, write hi/lo bf16
// planes + x2/y2.  v tiles: swapped-operand MFMA -> transposed coalesced store.
__global__ __launch_bounds__(256) void gemm_qkv(
        const float* __restrict__ x, const ushort* __restrict__ Wh,
        const ushort* __restrict__ Wl, const float* __restrict__ kcurv,
        ushort* __restrict__ qh, ushort* __restrict__ ql,
        ushort* __restrict__ kh, ushort* __restrict__ kl,
        ushort* __restrict__ vT, float* __restrict__ x2g,
        float* __restrict__ y2g) {
    __shared__ ushort Ah[128 * 40], Al[128 * 40], Bh[128 * 40], Bl[128 * 40];
    const int tid = threadIdx.x, lane = tid & 63, wv = tid >> 6;
    const int wr = wv >> 1, wc = wv & 1, lr = lane & 15, lg = lane >> 4;
    const int m0 = blockIdx.y * 128, n0 = blockIdx.x * 128;
    const bool isV = (n0 >= 2 * CC);
    const int srow = tid >> 1, sk0 = (tid & 1) * 16;
    const float* Ap = x + (size_t)(m0 + srow) * CC + sk0;
    const ushort* Bhp = Wh + (size_t)(n0 + srow) * CC + sk0;
    const ushort* Blp = Wl + (size_t)(n0 + srow) * CC + sk0;

    f32x4 acc[4][4] = {};
    float4 av[4];
    bf16x8 bhv[2], blv[2];
#pragma unroll
    for (int q = 0; q < 4; ++q) av[q] = *(const float4*)(Ap + 4 * q);
    bhv[0] = *(const bf16x8*)(Bhp);
    bhv[1] = *(const bf16x8*)(Bhp + 8);
    if (!isV) {
        blv[0] = *(const bf16x8*)(Blp);
        blv[1] = *(const bf16x8*)(Blp + 8);
    }

    for (int kk = 0; kk < CC; kk += 32) {
        __syncthreads();
#pragma unroll
        for (int q = 0; q < 4; ++q) {
            ull hp, lp;
            split4(av[q], hp, lp);
            *(ull*)&Ah[srow * 40 + sk0 + 4 * q] = hp;
            if (!isV) *(ull*)&Al[srow * 40 + sk0 + 4 * q] = lp;
        }
        *(bf16x8*)&Bh[srow * 40 + sk0] = bhv[0];
        *(bf16x8*)&Bh[srow * 40 + sk0 + 8] = bhv[1];
        if (!isV) {
            *(bf16x8*)&Bl[srow * 40 + sk0] = blv[0];
            *(bf16x8*)&Bl[srow * 40 + sk0 + 8] = blv[1];
        }
        __syncthreads();
        if (kk + 32 < CC) {
#pragma unroll
            for (int q = 0; q < 4; ++q)
                av[q] = *(const float4*)(Ap + kk + 32 + 4 * q);
            bhv[0] = *(const bf16x8*)(Bhp + kk + 32);
            bhv[1] = *(const bf16x8*)(Bhp + kk + 40);
            if (!isV) {
                blv[0] = *(const bf16x8*)(Blp + kk + 32);
                blv[1] = *(const bf16x8*)(Blp + kk + 40);
            }
        }
        if (!isV) {
            bf16x8 a_h[4], a_l[4];
#pragma unroll
            for (int m = 0; m < 4; ++m) {
                const int off = (wr * 64 + m * 16 + lr) * 40 + lg * 8;
                a_h[m] = *(const bf16x8*)&Ah[off];
                a_l[m] = *(const bf16x8*)&Al[off];
            }
#pragma unroll
            for (int n = 0; n < 4; ++n) {
                const int off = (wc * 64 + n * 16 + lr) * 40 + lg * 8;
                bf16x8 b_h = *(const bf16x8*)&Bh[off];
                bf16x8 b_l = *(const bf16x8*)&Bl[off];
#pragma unroll
                for (int m = 0; m < 4; ++m) {
                    acc[m][n] = MFMA(a_h[m], b_h, acc[m][n]);
                    acc[m][n] = MFMA(a_h[m], b_l, acc[m][n]);
                    acc[m][n] = MFMA(a_l[m], b_h, acc[m][n]);
                }
            }
        } else {
            bf16x8 a_h[4], b_h[4];
#pragma unroll
            for (int m = 0; m < 4; ++m)
                a_h[m] = *(const bf16x8*)&Ah[(wr * 64 + m * 16 + lr) * 40 + lg * 8];
#pragma unroll
            for (int n = 0; n < 4; ++n)
                b_h[n] = *(const bf16x8*)&Bh[(wc * 64 + n * 16 + lr) * 40 + lg * 8];
            // swapped operands: D rows = W(v)-rows (d), cols = tokens
#pragma unroll
            for (int n = 0; n < 4; ++n)
#pragma unroll
                for (int m = 0; m < 4; ++m)
                    acc[n][m] = MFMA(b_h[n], a_h[m], acc[n][m]);
        }
    }
    // ---- epilogue ----
    if (isV) {
        const int hd = (n0 - 2 * CC) / 64 + wc;
#pragma unroll
        for (int n = 0; n < 4; ++n)
#pragma unroll
            for (int m = 0; m < 4; ++m)
#pragma unroll
                for (int r = 0; r < 4; ++r) {
                    const int dl = n * 16 + lg * 4 + r;
                    const int tok = m0 + wr * 64 + m * 16 + lr;
                    vT[(size_t)(hd * 64 + dl) * 4096 + tok] = f2bf(acc[n][m][r]);
                }
    } else {
        const bool isQ = (n0 < CC);
        const int hd = (isQ ? n0 : n0 - CC) / 64 + wc;
        ushort* ph = isQ ? qh : kh;
        ushort* pl = isQ ? ql : kl;
        float* sg = isQ ? x2g : y2g;
        const float kcv = kcurv[hd];
        const float mxn = (1.0f - PROJ_EPSF) / sqrtf(kcv);
        const float mxn2 = mxn * mxn;
#pragma unroll
        for (int m = 0; m < 4; ++m)
#pragma unroll
            for (int r = 0; r < 4; ++r) {
                float s = 0.f;
#pragma unroll
                for (int n = 0; n < 4; ++n) s = fmaf(acc[m][n][r], acc[m][n][r], s);
                s += __shfl_xor(s, 1);
                s += __shfl_xor(s, 2);
                s += __shfl_xor(s, 4);
                s += __shfl_xor(s, 8);
                float scale = 1.0f, x2v = s;
                if (s > mxn2) {
                    scale = mxn * __builtin_amdgcn_rcpf(sqrtf(s));
                    x2v = s * scale * scale;
                }
                const int tok = m0 + wr * 64 + m * 16 + lg * 4 + r;
                const size_t rowb = (size_t)tok * CC + (isQ ? n0 : n0 - CC) + wc * 64;
#pragma unroll
                for (int n = 0; n < 4; ++n) {
                    const float v = acc[m][n][r] * scale;
                    const ushort hb = f2bf(v);
                    ph[rowb + n * 16 + lr] = hb;
                    pl[rowb + n * 16 + lr] = f2bf(v - bf2f(hb));
                }
                if (lr == 0)
                    sg[(size_t)((tok >> 10) * HH + hd) * TT + (tok & 1023)] = x2v;
            }
    }
}

// ---------------- barrier-free fused hyperbolic attention ----------------
// 256 thr = 4 independent waves; wave owns 16 q-rows. All operands direct
// from global bf16 planes as MFMA fragments; only wei D->A transpose uses
// per-wave-private LDS (no __syncthreads anywhere).
__global__ __launch_bounds__(256) void hyp_attn(
        const ushort* __restrict__ qh, const ushort* __restrict__ ql,
        const ushort* __restrict__ kh, const ushort* __restrict__ kl,
        const ushort* __restrict__ vT, const float* __restrict__ x2g,
        const float* __restrict__ y2g, const float* __restrict__ kcurv,
        float* __restrict__ y) {
    const int rgq = 15 - (int)blockIdx.x;   // long blocks first
    const int h = blockIdx.y, b = blockIdx.z;
    const int tid = threadIdx.x, lane = tid & 63, wv = tid >> 6;
    const int lr = lane & 15, lg = lane >> 4;
    const int rg = rgq * 4 + wv;            // row-group 0..63 (16 rows)
    const int bh = b * HH + h;

    __shared__ ushort wt[4][16 * 72];
    ushort* wtw = wt[wv];

    const float kc = kcurv[h];
    const float sk = sqrtf(kc);
    const float distc = LN2F / sk;
    const float twokc = 2.0f * kc;

    // Q fragments (projected hi/lo), x2 per row
    const size_t qrb = (size_t)(b * TT + rg * 16 + lr) * CC + h * 64 + lg * 8;
    bf16x8 qH[2] = { *(const bf16x8*)(qh + qrb), *(const bf16x8*)(qh + qrb + 32) };
    bf16x8 qL[2] = { *(const bf16x8*)(ql + qrb), *(const bf16x8*)(ql + qrb + 32) };
    const float4 x2v = *(const float4*)&x2g[(size_t)bh * TT + rg * 16 + lg * 4];
    const float x2a[4] = { x2v.x, x2v.y, x2v.z, x2v.w };
    float kx2[4], Bc[4], Bc2[4];
#pragma unroll
    for (int r = 0; r < 4; ++r) {
        kx2[r] = kc * x2a[r];
        Bc[r] = 1.0f - kx2[r];
        Bc2[r] = Bc[r] * Bc[r];
    }

    f32x4 pv[4] = {};
    float den[4] = {};

    for (int jt = 0; jt <= rgq; ++jt) {
        const int j0 = jt * 64;
        const bool maskT = (jt == rgq);
        bf16x8 kHf[4][2], kLf[4][2];
        float y2n[4];
#pragma unroll
        for (int n = 0; n < 4; ++n) {
            const size_t rb = (size_t)(b * TT + j0 + n * 16 + lr) * CC + h * 64 + lg * 8;
            kHf[n][0] = *(const bf16x8*)(kh + rb);
            kHf[n][1] = *(const bf16x8*)(kh + rb + 32);
            kLf[n][0] = *(const bf16x8*)(kl + rb);
            kLf[n][1] = *(const bf16x8*)(kl + rb + 32);
            y2n[n] = y2g[(size_t)bh * TT + j0 + n * 16 + lr];
        }
        f32x4 sacc[4] = {};
#pragma unroll
        for (int n = 0; n < 4; ++n)
#pragma unroll
            for (int ks = 0; ks < 2; ++ks) {
                sacc[n] = MFMA(qH[ks], kHf[n][ks], sacc[n]);
                sacc[n] = MFMA(qH[ks], kLf[n][ks], sacc[n]);
                sacc[n] = MFMA(qL[ks], kHf[n][ks], sacc[n]);
            }
        // V fragments: issue early, consumed after transform
        bf16x8 vF[4][2];
#pragma unroll
        for (int n = 0; n < 4; ++n) {
            const size_t vb = (size_t)(h * 64 + n * 16 + lr) * 4096 + b * TT + j0 + lg * 8;
            vF[n][0] = *(const bf16x8*)(vT + vb);
            vF[n][1] = *(const bf16x8*)(vT + vb + 32);
        }
        // ---- hyperbolic transform -> wei (bf16) ----
        float wsum[4] = {};
#pragma unroll
        for (int n = 0; n < 4; ++n) {
            const float y2 = y2n[n];
            const float ky2 = kc * y2;
            const float p1 = 1.0f + ky2;
            const int jg = j0 + n * 16 + lr;
#pragma unroll
            for (int r = 0; r < 4; ++r) {
                const float xy = sacc[n][r];
                const float t2 = twokc * xy;
                const float Aa = p1 - t2;
                const float dn = fmaf(kx2[r], ky2, 1.0f) - t2;
                const float BA = Bc[r] * xy;
                const float c1 = fmaf(Bc2[r], y2, -2.0f * (Aa * BA));
                const float num2 = fmaf(Aa * Aa, x2a[r], c1);
                const float madd = sqrtf(fmaxf(num2, MIN_NORMF)) *
                                   __builtin_amdgcn_rcpf(fmaxf(dn, MIN_NORMF));
                const float t = fminf(sk * madd, 1.0f - ATANH_EPSF);
                const float dist = distc * __builtin_amdgcn_logf(
                                       (1.0f + t) * __builtin_amdgcn_rcpf(1.0f - t));
                float w = __builtin_amdgcn_rcpf(fmaf(dist, dist, WEI_EPSF));
                if (maskT && (jg > rg * 16 + lg * 4 + r)) w = 0.0f;
                const ushort wb = f2bf(w);
                wtw[(lg * 4 + r) * 72 + n * 16 + lr] = wb;
                wsum[r] += bf2f(wb);
            }
        }
#pragma unroll
        for (int r = 0; r < 4; ++r) {
            float s = wsum[r];
            s += __shfl_xor(s, 1);
            s += __shfl_xor(s, 2);
            s += __shfl_xor(s, 4);
            s += __shfl_xor(s, 8);
            den[r] += s;
        }
        // ---- PV ----
        bf16x8 pw[2];
        pw[0] = *(const bf16x8*)&wtw[lr * 72 + lg * 8];
        pw[1] = *(const bf16x8*)&wtw[lr * 72 + 32 + lg * 8];
#pragma unroll
        for (int n = 0; n < 4; ++n) {
            pv[n] = MFMA(pw[0], vF[n][0], pv[n]);
            pv[n] = MFMA(pw[1], vF[n][1], pv[n]);
        }
    }
    // ---- epilogue ----
#pragma unroll
    for (int r = 0; r < 4; ++r) {
        const float iv = __builtin_amdgcn_rcpf(den[r]);
        const size_t rowb = (size_t)(b * TT + rg * 16 + lg * 4 + r) * CC + h * 64;
#pragma unroll
        for (int n = 0; n < 4; ++n)
            y[rowb + n * 16 + lr] = pv[n][r] * iv;
    }
}

// ---------------- output GEMM: out = y @ Wproj^T (hi/lo, f32 out) ----------------
__global__ __launch_bounds__(256) void gemm_out(const float* __restrict__ A,
                                                const ushort* __restrict__ Wh,
                                                const ushort* __restrict__ Wl,
                                                float* __restrict__ C) {
    __shared__ ushort Ah[128 * 40], Al[128 * 40], Bh[128 * 40], Bl[128 * 40];
    const int tid = threadIdx.x, lane = tid & 63, wv = tid >> 6;
    const int wr = wv >> 1, wc = wv & 1, lr = lane & 15, lg = lane >> 4;
    const int m0 = blockIdx.y * 128, n0 = blockIdx.x * 128;
    const int srow = tid >> 1, sk0 = (tid & 1) * 16;
    const float* Ap = A + (size_t)(m0 + srow) * CC + sk0;
    const ushort* Bhp = Wh + (size_t)(n0 + srow) * CC + sk0;
    const ushort* Blp = Wl + (size_t)(n0 + srow) * CC + sk0;

    f32x4 acc[4][4] = {};
    float4 av[4];
    bf16x8 bhv[2], blv[2];
#pragma unroll
    for (int q = 0; q < 4; ++q) av[q] = *(const float4*)(Ap + 4 * q);
    bhv[0] = *(const bf16x8*)(Bhp);
    bhv[1] = *(const bf16x8*)(Bhp + 8);
    blv[0] = *(const bf16x8*)(Blp);
    blv[1] = *(const bf16x8*)(Blp + 8);

    for (int kk = 0; kk < CC; kk += 32) {
        __syncthreads();
#pragma unroll
        for (int q = 0; q < 4; ++q) {
            ull hp, lp;
            split4(av[q], hp, lp);
            *(ull*)&Ah[srow * 40 + sk0 + 4 * q] = hp;
            *(ull*)&Al[srow * 40 + sk0 + 4 * q] = lp;
        }
        *(bf16x8*)&Bh[srow * 40 + sk0] = bhv[0];
        *(bf16x8*)&Bh[srow * 40 + sk0 + 8] = bhv[1];
        *(bf16x8*)&Bl[srow * 40 + sk0] = blv[0];
        *(bf16x8*)&Bl[srow * 40 + sk0 + 8] = blv[1];
        __syncthreads();
        if (kk + 32 < CC) {
#pragma unroll
            for (int q = 0; q < 4; ++q)
                av[q] = *(const float4*)(Ap + kk + 32 + 4 * q);
            bhv[0] = *(const bf16x8*)(Bhp + kk + 32);
            bhv[1] = *(const bf16x8*)(Bhp + kk + 40);
            blv[0] = *(const bf16x8*)(Blp + kk + 32);
            blv[1] = *(const bf16x8*)(Blp + kk + 40);
        }
        bf16x8 a_h[4], a_l[4];
#pragma unroll
        for (int m = 0; m < 4; ++m) {
            const int off = (wr * 64 + m * 16 + lr) * 40 + lg * 8;
            a_h[m] = *(const bf16x8*)&Ah[off];
            a_l[m] = *(const bf16x8*)&Al[off];
        }
#pragma unroll
        for (int n = 0; n < 4; ++n) {
            const int off = (wc * 64 + n * 16 + lr) * 40 + lg * 8;
            bf16x8 b_h = *(const bf16x8*)&Bh[off];
            bf16x8 b_l = *(const bf16x8*)&Bl[off];
#pragma unroll
            for (int m = 0; m < 4; ++m) {
                acc[m][n] = MFMA(a_h[m], b_h, acc[m][n]);
                acc[m][n] = MFMA(a_h[m], b_l, acc[m][n]);
                acc[m][n] = MFMA(a_l[m], b_h, acc[m][n]);
            }
        }
    }
#pragma unroll
    for (int m = 0; m < 4; ++m)
#pragma unroll
        for (int n = 0; n < 4; ++n)
#pragma unroll
            for (int r = 0; r < 4; ++r)
                C[(size_t)(m0 + wr * 64 + m * 16 + lg * 4 + r) * CC + n0 + wc * 64 + n * 16 + lr] =
                    acc[m][n][r];
}

extern "C" void kernel_launch(void* const* d_in, const int* in_sizes, int n_in,
                              void* d_out, int out_size, void* d_ws, size_t ws_size,
                              hipStream_t stream) {
    const float* x     = (const float*)d_in[0];   // (4,1024,768)
    const float* Wqkv  = (const float*)d_in[1];   // (2304,768)
    const float* Wproj = (const float*)d_in[2];   // (768,768)
    const float* kcurv = (const float*)d_in[3];   // (1,12,1,1)
    float* out = (float*)d_out;

    const size_t PL = (size_t)4096 * CC;          // 3,145,728 elems per plane
    ushort* qh = (ushort*)d_ws;
    ushort* ql = qh + PL;
    ushort* kh = ql + PL;
    ushort* kl = kh + PL;
    ushort* vT = kl + PL;                         // [12][64][4096]
    float*  yb = (float*)(vT + PL);               // 4096 x 768 f32
    ushort* Wqh = (ushort*)yb;                    // overlap y (dead before attn)
    ushort* Wql = Wqh + (size_t)2304 * CC;
    ushort* Wph = (ushort*)(yb + PL);
    ushort* Wpl = Wph + (size_t)CC * CC;
    float* x2g = (float*)(Wpl + (size_t)CC * CC); // [48][1024]
    float* y2g = x2g + 48 * TT;

    wprep<<<(2304 * CC / 4 + 255) / 256, 256, 0, stream>>>(Wqkv, Wqh, Wql, 2304 * CC / 4);
    wprep<<<(CC * CC / 4 + 255) / 256, 256, 0, stream>>>(Wproj, Wph, Wpl, CC * CC / 4);
    gemm_qkv<<<dim3(18, 32), 256, 0, stream>>>(x, Wqh, Wql, kcurv,
                                               qh, ql, kh, kl, vT, x2g, y2g);
    hyp_attn<<<dim3(16, HH, BBATCH), 256, 0, stream>>>(qh, ql, kh, kl, vT,
                                                       x2g, y2g, kcurv, yb);
    gemm_out<<<dim3(6, 32), 256, 0, stream>>>(yb, Wph, Wpl, out);
}

// Round 5
// 225.779 us; speedup vs baseline: 3.2573x; 1.0646x over previous
//
#include <hip/hip_runtime.h>
#include <hip/hip_bf16.h>
#include <math.h>

#define PROJ_EPSF 0.004f
#define MIN_NORMF 1e-15f
#define ATANH_EPSF 1e-5f
#define WEI_EPSF 1e-3f
#define LN2F 0.69314718055994531f

#define TT 1024
#define CC 768
#define HH 12
#define BBATCH 4

typedef unsigned long long ull;
typedef __attribute__((ext_vector_type(4))) float f32x4;
typedef __attribute__((ext_vector_type(8))) short bf16x8;

#define MFMA(a, b, c) __builtin_amdgcn_mfma_f32_16x16x32_bf16(a, b, c, 0, 0, 0)

static __device__ __forceinline__ uint cvtpk(float a, float b) {
    uint r;
    asm("v_cvt_pk_bf16_f32 %0, %1, %2" : "=v"(r) : "v"(a), "v"(b));
    return r;
}
static __device__ __forceinline__ ushort f2bf(float f) {
    uint u = __float_as_uint(f);
    u += 0x7fffu + ((u >> 16) & 1u);
    return (ushort)(u >> 16);
}
static __device__ __forceinline__ float bf2f(ushort h) {
    return __uint_as_float(((uint)h) << 16);
}
// split float4 -> 4 bf16 hi (packed u64) + 4 bf16 residual-lo (packed u64)
static __device__ __forceinline__ void split4(const float4& f, ull& hp, ull& lp) {
    uint h01 = cvtpk(f.x, f.y), h23 = cvtpk(f.z, f.w);
    float r0 = f.x - __uint_as_float(h01 << 16);
    float r1 = f.y - __uint_as_float(h01 & 0xffff0000u);
    float r2 = f.z - __uint_as_float(h23 << 16);
    float r3 = f.w - __uint_as_float(h23 & 0xffff0000u);
    uint l01 = cvtpk(r0, r1), l23 = cvtpk(r2, r3);
    hp = ((ull)h23 << 32) | h01;
    lp = ((ull)l23 << 32) | l01;
}

// ---------------- weight prep: f32 -> bf16 hi/lo planes ----------------
__global__ __launch_bounds__(256) void wprep(const float* __restrict__ W,
                                             ushort* __restrict__ Wh,
                                             ushort* __restrict__ Wl, int n4) {
    int i = blockIdx.x * 256 + threadIdx.x;
    if (i < n4) {
        float4 f = ((const float4*)W)[i];
        ull hp, lp;
        split4(f, hp, lp);
        ((ull*)Wh)[i] = hp;
        ((ull*)Wl)[i] = lp;
    }
}

// ---------------- fused QKV GEMM + Poincare projection + layout ----------------
__global__ __launch_bounds__(256) void gemm_qkv(
        const float* __restrict__ x, const ushort* __restrict__ Wh,
        const ushort* __restrict__ Wl, const float* __restrict__ kcurv,
        ushort* __restrict__ qh, ushort* __restrict__ ql,
        ushort* __restrict__ kh, ushort* __restrict__ kl,
        ushort* __restrict__ vT, float* __restrict__ x2g,
        float* __restrict__ y2g) {
    __shared__ ushort Ah[128 * 40], Al[128 * 40], Bh[128 * 40], Bl[128 * 40];
    const int tid = threadIdx.x, lane = tid & 63, wv = tid >> 6;
    const int wr = wv >> 1, wc = wv & 1, lr = lane & 15, lg = lane >> 4;
    const int m0 = blockIdx.y * 128, n0 = blockIdx.x * 128;
    const bool isV = (n0 >= 2 * CC);
    const int srow = tid >> 1, sk0 = (tid & 1) * 16;
    const float* Ap = x + (size_t)(m0 + srow) * CC + sk0;
    const ushort* Bhp = Wh + (size_t)(n0 + srow) * CC + sk0;
    const ushort* Blp = Wl + (size_t)(n0 + srow) * CC + sk0;

    f32x4 acc[4][4] = {};
    float4 av[4];
    bf16x8 bhv[2], blv[2];
#pragma unroll
    for (int q = 0; q < 4; ++q) av[q] = *(const float4*)(Ap + 4 * q);
    bhv[0] = *(const bf16x8*)(Bhp);
    bhv[1] = *(const bf16x8*)(Bhp + 8);
    if (!isV) {
        blv[0] = *(const bf16x8*)(Blp);
        blv[1] = *(const bf16x8*)(Blp + 8);
    }

    for (int kk = 0; kk < CC; kk += 32) {
        __syncthreads();
#pragma unroll
        for (int q = 0; q < 4; ++q) {
            ull hp, lp;
            split4(av[q], hp, lp);
            *(ull*)&Ah[srow * 40 + sk0 + 4 * q] = hp;
            if (!isV) *(ull*)&Al[srow * 40 + sk0 + 4 * q] = lp;
        }
        *(bf16x8*)&Bh[srow * 40 + sk0] = bhv[0];
        *(bf16x8*)&Bh[srow * 40 + sk0 + 8] = bhv[1];
        if (!isV) {
            *(bf16x8*)&Bl[srow * 40 + sk0] = blv[0];
            *(bf16x8*)&Bl[srow * 40 + sk0 + 8] = blv[1];
        }
        __syncthreads();
        if (kk + 32 < CC) {
#pragma unroll
            for (int q = 0; q < 4; ++q)
                av[q] = *(const float4*)(Ap + kk + 32 + 4 * q);
            bhv[0] = *(const bf16x8*)(Bhp + kk + 32);
            bhv[1] = *(const bf16x8*)(Bhp + kk + 40);
            if (!isV) {
                blv[0] = *(const bf16x8*)(Blp + kk + 32);
                blv[1] = *(const bf16x8*)(Blp + kk + 40);
            }
        }
        if (!isV) {
            bf16x8 a_h[4], a_l[4];
#pragma unroll
            for (int m = 0; m < 4; ++m) {
                const int off = (wr * 64 + m * 16 + lr) * 40 + lg * 8;
                a_h[m] = *(const bf16x8*)&Ah[off];
                a_l[m] = *(const bf16x8*)&Al[off];
            }
#pragma unroll
            for (int n = 0; n < 4; ++n) {
                const int off = (wc * 64 + n * 16 + lr) * 40 + lg * 8;
                bf16x8 b_h = *(const bf16x8*)&Bh[off];
                bf16x8 b_l = *(const bf16x8*)&Bl[off];
#pragma unroll
                for (int m = 0; m < 4; ++m) {
                    acc[m][n] = MFMA(a_h[m], b_h, acc[m][n]);
                    acc[m][n] = MFMA(a_h[m], b_l, acc[m][n]);
                    acc[m][n] = MFMA(a_l[m], b_h, acc[m][n]);
                }
            }
        } else {
            bf16x8 a_h[4], b_h[4];
#pragma unroll
            for (int m = 0; m < 4; ++m)
                a_h[m] = *(const bf16x8*)&Ah[(wr * 64 + m * 16 + lr) * 40 + lg * 8];
#pragma unroll
            for (int n = 0; n < 4; ++n)
                b_h[n] = *(const bf16x8*)&Bh[(wc * 64 + n * 16 + lr) * 40 + lg * 8];
#pragma unroll
            for (int n = 0; n < 4; ++n)
#pragma unroll
                for (int m = 0; m < 4; ++m)
                    acc[n][m] = MFMA(b_h[n], a_h[m], acc[n][m]);
        }
    }
    // ---- epilogue ----
    if (isV) {
        const int hd = (n0 - 2 * CC) / 64 + wc;
#pragma unroll
        for (int n = 0; n < 4; ++n)
#pragma unroll
            for (int m = 0; m < 4; ++m)
#pragma unroll
                for (int r = 0; r < 4; ++r) {
                    const int dl = n * 16 + lg * 4 + r;
                    const int tok = m0 + wr * 64 + m * 16 + lr;
                    vT[(size_t)(hd * 64 + dl) * 4096 + tok] = f2bf(acc[n][m][r]);
                }
    } else {
        const bool isQ = (n0 < CC);
        const int hd = (isQ ? n0 : n0 - CC) / 64 + wc;
        ushort* ph = isQ ? qh : kh;
        ushort* pl = isQ ? ql : kl;
        float* sg = isQ ? x2g : y2g;
        const float kcv = kcurv[hd];
        const float mxn = (1.0f - PROJ_EPSF) / sqrtf(kcv);
        const float mxn2 = mxn * mxn;
#pragma unroll
        for (int m = 0; m < 4; ++m)
#pragma unroll
            for (int r = 0; r < 4; ++r) {
                float s = 0.f;
#pragma unroll
                for (int n = 0; n < 4; ++n) s = fmaf(acc[m][n][r], acc[m][n][r], s);
                s += __shfl_xor(s, 1);
                s += __shfl_xor(s, 2);
                s += __shfl_xor(s, 4);
                s += __shfl_xor(s, 8);
                float scale = 1.0f, x2v = s;
                if (s > mxn2) {
                    scale = mxn * __builtin_amdgcn_rcpf(sqrtf(s));
                    x2v = s * scale * scale;
                }
                const int tok = m0 + wr * 64 + m * 16 + lg * 4 + r;
                const size_t rowb = (size_t)tok * CC + (isQ ? n0 : n0 - CC) + wc * 64;
#pragma unroll
                for (int n = 0; n < 4; ++n) {
                    const float v = acc[m][n][r] * scale;
                    const ushort hb = f2bf(v);
                    ph[rowb + n * 16 + lr] = hb;
                    pl[rowb + n * 16 + lr] = f2bf(v - bf2f(hb));
                }
                if (lr == 0)
                    sg[(size_t)((tok >> 10) * HH + hd) * TT + (tok & 1023)] = x2v;
            }
    }
}

// ---------------- load-balanced split-j fused hyperbolic attention ----------------
// Block = 4 waves, handles row-group pair (pA, 63-pA): uniform 17 tiles/block.
// Waves 0,1 -> rgA (even/odd jt); waves 2,3 -> rgB. One barrier to combine.
__global__ __launch_bounds__(256) void hyp_attn(
        const ushort* __restrict__ qh, const ushort* __restrict__ ql,
        const ushort* __restrict__ kh, const ushort* __restrict__ kl,
        const ushort* __restrict__ vT, const float* __restrict__ x2g,
        const float* __restrict__ y2g, const float* __restrict__ kcurv,
        ushort* __restrict__ yh, ushort* __restrict__ yl) {
    const int pA = blockIdx.x;              // 0..31
    const int h = blockIdx.y, b = blockIdx.z;
    const int tid = threadIdx.x, lane = tid & 63, wv = tid >> 6;
    const int lr = lane & 15, lg = lane >> 4;
    const int half = wv >> 1, parity = wv & 1;
    const int rg = half ? (63 - pA) : pA;   // 16-row group 0..63
    const int rgq = rg >> 2;                // last key-tile index
    const int bh = b * HH + h;

    __shared__ ushort wt[4][16 * 72];
    __shared__ float cmb[2][16][64];
    __shared__ float dcmb[2][16];
    ushort* wtw = wt[wv];

    const float kc = kcurv[h];
    const float sk = sqrtf(kc);
    const float distc = LN2F / sk;
    const float d2c = distc * distc;
    const float twokc = 2.0f * kc;
    const float cA = 1.0f - ATANH_EPSF;

    // Q fragments (projected hi/lo), x2 per row
    const size_t qrb = (size_t)(b * TT + rg * 16 + lr) * CC + h * 64 + lg * 8;
    bf16x8 qH[2] = { *(const bf16x8*)(qh + qrb), *(const bf16x8*)(qh + qrb + 32) };
    bf16x8 qL[2] = { *(const bf16x8*)(ql + qrb), *(const bf16x8*)(ql + qrb + 32) };
    const float4 x2v = *(const float4*)&x2g[(size_t)bh * TT + rg * 16 + lg * 4];
    const float x2a[4] = { x2v.x, x2v.y, x2v.z, x2v.w };
    float kx2[4], Bc[4], Bc2[4];
#pragma unroll
    for (int r = 0; r < 4; ++r) {
        kx2[r] = kc * x2a[r];
        Bc[r] = 1.0f - kx2[r];
        Bc2[r] = Bc[r] * Bc[r];
    }

    f32x4 pv[4] = {};
    float wsum[4] = {};

    for (int jt = parity; jt <= rgq; jt += 2) {
        const int j0 = jt * 64;
        const bool maskT = (jt == rgq);
        bf16x8 kHf[4][2], kLf[4][2];
        float y2n[4];
#pragma unroll
        for (int n = 0; n < 4; ++n) {
            const size_t rb = (size_t)(b * TT + j0 + n * 16 + lr) * CC + h * 64 + lg * 8;
            kHf[n][0] = *(const bf16x8*)(kh + rb);
            kHf[n][1] = *(const bf16x8*)(kh + rb + 32);
            kLf[n][0] = *(const bf16x8*)(kl + rb);
            kLf[n][1] = *(const bf16x8*)(kl + rb + 32);
            y2n[n] = y2g[(size_t)bh * TT + j0 + n * 16 + lr];
        }
        f32x4 sacc[4] = {};
#pragma unroll
        for (int n = 0; n < 4; ++n)
#pragma unroll
            for (int ks = 0; ks < 2; ++ks) {
                sacc[n] = MFMA(qH[ks], kHf[n][ks], sacc[n]);
                sacc[n] = MFMA(qH[ks], kLf[n][ks], sacc[n]);
                sacc[n] = MFMA(qL[ks], kHf[n][ks], sacc[n]);
            }
        // V fragments: issue early, consumed after transform
        bf16x8 vF[4][2];
#pragma unroll
        for (int n = 0; n < 4; ++n) {
            const size_t vb = (size_t)(h * 64 + n * 16 + lr) * 4096 + b * TT + j0 + lg * 8;
            vF[n][0] = *(const bf16x8*)(vT + vb);
            vF[n][1] = *(const bf16x8*)(vT + vb + 32);
        }
        // ---- hyperbolic transform -> wei (bf16) ----
#pragma unroll
        for (int n = 0; n < 4; ++n) {
            const float y2 = y2n[n];
            const float ky2 = kc * y2;
            const float p1 = 1.0f + ky2;
            const int jg = j0 + n * 16 + lr;
#pragma unroll
            for (int r = 0; r < 4; ++r) {
                const float xy = sacc[n][r];
                const float t2 = twokc * xy;
                const float Aa = p1 - t2;
                const float dn = fmaxf(fmaf(kx2[r], ky2, 1.0f) - t2, MIN_NORMF);
                const float ABxy = Aa * (Bc[r] * xy);
                const float c1 = fmaf(Bc2[r], y2, -2.0f * ABxy);
                const float num2 = fmaf(Aa * Aa, x2a[r], c1);
                const float s = sqrtf(fmaxf(num2, MIN_NORMF));
                const float sm = fminf(sk * s, cA * dn);
                const float L = __builtin_amdgcn_logf((dn + sm) *
                                    __builtin_amdgcn_rcpf(dn - sm));
                float w = __builtin_amdgcn_rcpf(fmaf(L * L, d2c, WEI_EPSF));
                if (maskT && (jg > rg * 16 + lg * 4 + r)) w = 0.0f;
                wtw[(lg * 4 + r) * 72 + n * 16 + lr] = f2bf(w);
                wsum[r] += w;
            }
        }
        // ---- PV ----
        bf16x8 pw[2];
        pw[0] = *(const bf16x8*)&wtw[lr * 72 + lg * 8];
        pw[1] = *(const bf16x8*)&wtw[lr * 72 + 32 + lg * 8];
#pragma unroll
        for (int n = 0; n < 4; ++n) {
            pv[n] = MFMA(pw[0], vF[n][0], pv[n]);
            pv[n] = MFMA(pw[1], vF[n][1], pv[n]);
        }
    }
    // ---- reduce den within wave (over lr lanes) ----
    float den[4];
#pragma unroll
    for (int r = 0; r < 4; ++r) {
        float s = wsum[r];
        s += __shfl_xor(s, 1);
        s += __shfl_xor(s, 2);
        s += __shfl_xor(s, 4);
        s += __shfl_xor(s, 8);
        den[r] = s;
    }
    // ---- combine even/odd partials ----
    if (parity == 1) {
#pragma unroll
        for (int n = 0; n < 4; ++n)
#pragma unroll
            for (int r = 0; r < 4; ++r)
                cmb[half][lg * 4 + r][n * 16 + lr] = pv[n][r];
        if (lr == 0)
#pragma unroll
            for (int r = 0; r < 4; ++r) dcmb[half][lg * 4 + r] = den[r];
    }
    __syncthreads();
    if (parity == 0) {
#pragma unroll
        for (int r = 0; r < 4; ++r) {
            const float dt = den[r] + dcmb[half][lg * 4 + r];
            const float iv = __builtin_amdgcn_rcpf(dt);
            const size_t rowb = (size_t)(b * TT + rg * 16 + lg * 4 + r) * CC + h * 64;
#pragma unroll
            for (int n = 0; n < 4; ++n) {
                const float val = (pv[n][r] + cmb[half][lg * 4 + r][n * 16 + lr]) * iv;
                const ushort hb = f2bf(val);
                yh[rowb + n * 16 + lr] = hb;
                yl[rowb + n * 16 + lr] = f2bf(val - bf2f(hb));
            }
        }
    }
}

// ---------------- output GEMM: out = y @ Wproj^T (pre-split A and B) ----------------
__global__ __launch_bounds__(256) void gemm_out(const ushort* __restrict__ Ahp,
                                                const ushort* __restrict__ Alp,
                                                const ushort* __restrict__ Wh,
                                                const ushort* __restrict__ Wl,
                                                float* __restrict__ C) {
    __shared__ ushort Ah[128 * 40], Al[128 * 40], Bh[128 * 40], Bl[128 * 40];
    const int tid = threadIdx.x, lane = tid & 63, wv = tid >> 6;
    const int wr = wv >> 1, wc = wv & 1, lr = lane & 15, lg = lane >> 4;
    const int m0 = blockIdx.y * 128, n0 = blockIdx.x * 128;
    const int srow = tid >> 1, sk0 = (tid & 1) * 16;
    const ushort* Ahq = Ahp + (size_t)(m0 + srow) * CC + sk0;
    const ushort* Alq = Alp + (size_t)(m0 + srow) * CC + sk0;
    const ushort* Bhp = Wh + (size_t)(n0 + srow) * CC + sk0;
    const ushort* Blp = Wl + (size_t)(n0 + srow) * CC + sk0;

    f32x4 acc[4][4] = {};
    bf16x8 ahv[2], alv[2], bhv[2], blv[2];
    ahv[0] = *(const bf16x8*)(Ahq);      ahv[1] = *(const bf16x8*)(Ahq + 8);
    alv[0] = *(const bf16x8*)(Alq);      alv[1] = *(const bf16x8*)(Alq + 8);
    bhv[0] = *(const bf16x8*)(Bhp);      bhv[1] = *(const bf16x8*)(Bhp + 8);
    blv[0] = *(const bf16x8*)(Blp);      blv[1] = *(const bf16x8*)(Blp + 8);

    for (int kk = 0; kk < CC; kk += 32) {
        __syncthreads();
        *(bf16x8*)&Ah[srow * 40 + sk0] = ahv[0];
        *(bf16x8*)&Ah[srow * 40 + sk0 + 8] = ahv[1];
        *(bf16x8*)&Al[srow * 40 + sk0] = alv[0];
        *(bf16x8*)&Al[srow * 40 + sk0 + 8] = alv[1];
        *(bf16x8*)&Bh[srow * 40 + sk0] = bhv[0];
        *(bf16x8*)&Bh[srow * 40 + sk0 + 8] = bhv[1];
        *(bf16x8*)&Bl[srow * 40 + sk0] = blv[0];
        *(bf16x8*)&Bl[srow * 40 + sk0 + 8] = blv[1];
        __syncthreads();
        if (kk + 32 < CC) {
            ahv[0] = *(const bf16x8*)(Ahq + kk + 32);
            ahv[1] = *(const bf16x8*)(Ahq + kk + 40);
            alv[0] = *(const bf16x8*)(Alq + kk + 32);
            alv[1] = *(const bf16x8*)(Alq + kk + 40);
            bhv[0] = *(const bf16x8*)(Bhp + kk + 32);
            bhv[1] = *(const bf16x8*)(Bhp + kk + 40);
            blv[0] = *(const bf16x8*)(Blp + kk + 32);
            blv[1] = *(const bf16x8*)(Blp + kk + 40);
        }
        bf16x8 a_h[4], a_l[4];
#pragma unroll
        for (int m = 0; m < 4; ++m) {
            const int off = (wr * 64 + m * 16 + lr) * 40 + lg * 8;
            a_h[m] = *(const bf16x8*)&Ah[off];
            a_l[m] = *(const bf16x8*)&Al[off];
        }
#pragma unroll
        for (int n = 0; n < 4; ++n) {
            const int off = (wc * 64 + n * 16 + lr) * 40 + lg * 8;
            bf16x8 b_h = *(const bf16x8*)&Bh[off];
            bf16x8 b_l = *(const bf16x8*)&Bl[off];
#pragma unroll
            for (int m = 0; m < 4; ++m) {
                acc[m][n] = MFMA(a_h[m], b_h, acc[m][n]);
                acc[m][n] = MFMA(a_h[m], b_l, acc[m][n]);
                acc[m][n] = MFMA(a_l[m], b_h, acc[m][n]);
            }
        }
    }
#pragma unroll
    for (int m = 0; m < 4; ++m)
#pragma unroll
        for (int n = 0; n < 4; ++n)
#pragma unroll
            for (int r = 0; r < 4; ++r)
                C[(size_t)(m0 + wr * 64 + m * 16 + lg * 4 + r) * CC + n0 + wc * 64 + n * 16 + lr] =
                    acc[m][n][r];
}

extern "C" void kernel_launch(void* const* d_in, const int* in_sizes, int n_in,
                              void* d_out, int out_size, void* d_ws, size_t ws_size,
                              hipStream_t stream) {
    const float* x     = (const float*)d_in[0];   // (4,1024,768)
    const float* Wqkv  = (const float*)d_in[1];   // (2304,768)
    const float* Wproj = (const float*)d_in[2];   // (768,768)
    const float* kcurv = (const float*)d_in[3];   // (1,12,1,1)
    float* out = (float*)d_out;

    const size_t PL = (size_t)4096 * CC;          // 3,145,728 elems per plane
    char* w = (char*)d_ws;
    // region 0 (12.58 MB): Wqkv planes during gemm_qkv, then yh/yl after attn
    ushort* Wqh = (ushort*)w;                     // 3.54 MB
    ushort* Wql = Wqh + (size_t)2304 * CC;        // 3.54 MB
    ushort* yh  = (ushort*)w;                     // 6.29 MB (reuse)
    ushort* yl  = yh + PL;                        // 6.29 MB
    ushort* qh  = (ushort*)(w + 2 * PL * 2);
    ushort* ql  = qh + PL;
    ushort* kh  = ql + PL;
    ushort* kl  = kh + PL;
    ushort* vT  = kl + PL;                        // [12][64][4096]
    ushort* Wph = vT + PL;
    ushort* Wpl = Wph + (size_t)CC * CC;
    float* x2g  = (float*)(Wpl + (size_t)CC * CC);   // [4][12][1024]
    float* y2g  = x2g + 48 * TT;

    wprep<<<2304 * CC / 4 / 256, 256, 0, stream>>>(Wqkv, Wqh, Wql, 2304 * CC / 4);
    wprep<<<CC * CC / 4 / 256, 256, 0, stream>>>(Wproj, Wph, Wpl, CC * CC / 4);
    gemm_qkv<<<dim3(18, 32), 256, 0, stream>>>(x, Wqh, Wql, kcurv,
                                               qh, ql, kh, kl, vT, x2g, y2g);
    hyp_attn<<<dim3(32, HH, BBATCH), 256, 0, stream>>>(qh, ql, kh, kl, vT,
                                                       x2g, y2g, kcurv, yh, yl);
    gemm_out<<<dim3(6, 32), 256, 0, stream>>>(yh, yl, Wph, Wpl, out);
}